// Round 1
// 2135.808 us; speedup vs baseline: 1.2941x; 1.2941x over previous
//
#include <hip/hip_runtime.h>
#include <hip/hip_bf16.h>

#define D_ 512
#define S_ 1024
#define B_ 8
#define V_ 32000
#define M_ 8192   // B_*S_

typedef __bf16 bf16x8 __attribute__((ext_vector_type(8)));
typedef float f32x4 __attribute__((ext_vector_type(4)));

__device__ __forceinline__ float sigf(float x) { return 1.0f / (1.0f + __expf(-x)); }

// Full-wave (64-lane) sum via DPP: 6 dependent VALU ops, result broadcast as
// SGPR via readlane(63). Replaces the ds_swizzle butterfly (6 dependent LDS
// ops, ~100cy each) with a ~50cy VALU chain. LLVM atomic-optimizer sequence.
__device__ __forceinline__ float wave_sum(float x) {
    x += __int_as_float(__builtin_amdgcn_update_dpp(0, __float_as_int(x), 0x111, 0xf, 0xf, false)); // row_shr:1
    x += __int_as_float(__builtin_amdgcn_update_dpp(0, __float_as_int(x), 0x112, 0xf, 0xf, false)); // row_shr:2
    x += __int_as_float(__builtin_amdgcn_update_dpp(0, __float_as_int(x), 0x114, 0xf, 0xf, false)); // row_shr:4
    x += __int_as_float(__builtin_amdgcn_update_dpp(0, __float_as_int(x), 0x118, 0xf, 0xf, false)); // row_shr:8
    x += __int_as_float(__builtin_amdgcn_update_dpp(0, __float_as_int(x), 0x142, 0xa, 0xf, false)); // row_bcast:15
    x += __int_as_float(__builtin_amdgcn_update_dpp(0, __float_as_int(x), 0x143, 0xc, 0xf, false)); // row_bcast:31
    return __int_as_float(__builtin_amdgcn_readlane(__float_as_int(x), 63));
}

// ---------------------------------------------------------------------------
// K1: embedding gather + 3 fp32 GEMMs.  z=0: f = sigmoid(emb@Wih + bh)
//                                       z=1: x = silu(emb@W1+b1) * (emb@W2+b2)
// BM=128, BN=64, BK=16, 256 threads, 8x4 micro-tile.
// ---------------------------------------------------------------------------
__global__ __launch_bounds__(256) void k1_fx(
    const int* __restrict__ tok, const float* __restrict__ E,
    const float* __restrict__ Wih, const float* __restrict__ bh,
    const float* __restrict__ W1, const float* __restrict__ b1v,
    const float* __restrict__ W2, const float* __restrict__ b2v,
    float* __restrict__ fO, float* __restrict__ xO)
{
    __shared__ float As[16][128];   // transposed A tile
    __shared__ float Bs0[16][64];
    __shared__ float Bs1[16][64];
    __shared__ int toks[128];
    const int tid = threadIdx.x;
    const int zi = blockIdx.z;
    const int m0 = blockIdx.x * 128;
    const int n0 = blockIdx.y * 64;
    if (tid < 128) toks[tid] = tok[m0 + tid];
    __syncthreads();
    const int ty = tid >> 4, tx = tid & 15;
    const int ar0 = tid >> 2, ak = (tid & 3) * 4;  // A stage: rows 0..63
    const int ar1 = ar0 + 64;                      // rows 64..127
    const int bk = tid >> 4, bn = (tid & 15) * 4;
    const float* WA = zi ? W1 : Wih;
    float acc0[8][4] = {};
    float acc1[8][4] = {};
    for (int k0 = 0; k0 < D_; k0 += 16) {
        float4 a0 = *(const float4*)(E + (size_t)toks[ar0] * D_ + k0 + ak);
        float4 a1 = *(const float4*)(E + (size_t)toks[ar1] * D_ + k0 + ak);
        float4 bv0 = *(const float4*)(WA + (size_t)(k0 + bk) * D_ + n0 + bn);
        float4 bv1 = make_float4(0.f, 0.f, 0.f, 0.f);
        if (zi) bv1 = *(const float4*)(W2 + (size_t)(k0 + bk) * D_ + n0 + bn);
        __syncthreads();
        As[ak + 0][ar0] = a0.x; As[ak + 1][ar0] = a0.y; As[ak + 2][ar0] = a0.z; As[ak + 3][ar0] = a0.w;
        As[ak + 0][ar1] = a1.x; As[ak + 1][ar1] = a1.y; As[ak + 2][ar1] = a1.z; As[ak + 3][ar1] = a1.w;
        *(float4*)&Bs0[bk][bn] = bv0;
        if (zi) *(float4*)&Bs1[bk][bn] = bv1;
        __syncthreads();
        #pragma unroll
        for (int k = 0; k < 16; ++k) {
            float4 av0 = *(const float4*)&As[k][ty * 8];
            float4 av1 = *(const float4*)&As[k][ty * 8 + 4];
            float4 bq0 = *(const float4*)&Bs0[k][tx * 4];
            float a[8] = {av0.x, av0.y, av0.z, av0.w, av1.x, av1.y, av1.z, av1.w};
            float bb[4] = {bq0.x, bq0.y, bq0.z, bq0.w};
            #pragma unroll
            for (int i = 0; i < 8; ++i)
                #pragma unroll
                for (int j = 0; j < 4; ++j)
                    acc0[i][j] += a[i] * bb[j];
            if (zi) {
                float4 bq1 = *(const float4*)&Bs1[k][tx * 4];
                float bc[4] = {bq1.x, bq1.y, bq1.z, bq1.w};
                #pragma unroll
                for (int i = 0; i < 8; ++i)
                    #pragma unroll
                    for (int j = 0; j < 4; ++j)
                        acc1[i][j] += a[i] * bc[j];
            }
        }
    }
    #pragma unroll
    for (int i = 0; i < 8; ++i) {
        const int r = m0 + ty * 8 + i;
        #pragma unroll
        for (int j = 0; j < 4; ++j) {
            const int c = n0 + tx * 4 + j;
            if (zi == 0) {
                fO[(size_t)r * D_ + c] = sigf(acc0[i][j] + bh[c]);
            } else {
                float u1 = acc0[i][j] + b1v[c];
                float u2 = acc1[i][j] + b2v[c];
                xO[(size_t)r * D_ + c] = u1 * sigf(u1) * u2;
            }
        }
    }
}

// ---------------------------------------------------------------------------
// K2: blocks 0..7: the sequential scan (one wave per batch).  Per-step LN via
// DPP wave reduction (no LDS), final LN fused -> bf16 xf.  4-deep register
// software pipeline (prefetch row t+4 issued right after consuming row t).
// Blocks 8..: E fp32->bf16 conversion (overlaps with the scan tail).
// ---------------------------------------------------------------------------
__global__ __launch_bounds__(64) void k2_scan(
    const float* __restrict__ gF, const float* __restrict__ gX,
    const float* __restrict__ lnG, const float* __restrict__ lnB,
    const float* __restrict__ h0p,
    const float* __restrict__ lfG, const float* __restrict__ lfB,
    const float* __restrict__ Ein,
    __hip_bfloat16* __restrict__ xfO, __hip_bfloat16* __restrict__ EbO)
{
    const int blk = blockIdx.x;
    const int lane = threadIdx.x;
    if (blk >= B_) {
        // E conversion: 16000 blocks x 256 float4 = 16.384M floats
        const float4* E4 = (const float4*)Ein;
        uint2* O2 = (uint2*)EbO;
        const size_t base = (size_t)(blk - B_) * 256;
        #pragma unroll
        for (int it = 0; it < 4; ++it) {
            size_t i4 = base + it * 64 + lane;
            float4 v = E4[i4];
            union { __hip_bfloat16 h[4]; uint2 u; } pk;
            pk.h[0] = __float2bfloat16(v.x); pk.h[1] = __float2bfloat16(v.y);
            pk.h[2] = __float2bfloat16(v.z); pk.h[3] = __float2bfloat16(v.w);
            O2[i4] = pk.u;
        }
        return;
    }
    const int dA = lane * 4;
    const int dB2 = 256 + lane * 4;
    float h[8], lg[8], lb[8], fg[8], fb[8];
    {
        float4 t0 = *(const float4*)(h0p + dA), t1 = *(const float4*)(h0p + dB2);
        h[0]=t0.x; h[1]=t0.y; h[2]=t0.z; h[3]=t0.w; h[4]=t1.x; h[5]=t1.y; h[6]=t1.z; h[7]=t1.w;
        t0 = *(const float4*)(lnG + dA); t1 = *(const float4*)(lnG + dB2);
        lg[0]=t0.x; lg[1]=t0.y; lg[2]=t0.z; lg[3]=t0.w; lg[4]=t1.x; lg[5]=t1.y; lg[6]=t1.z; lg[7]=t1.w;
        t0 = *(const float4*)(lnB + dA); t1 = *(const float4*)(lnB + dB2);
        lb[0]=t0.x; lb[1]=t0.y; lb[2]=t0.z; lb[3]=t0.w; lb[4]=t1.x; lb[5]=t1.y; lb[6]=t1.z; lb[7]=t1.w;
        t0 = *(const float4*)(lfG + dA); t1 = *(const float4*)(lfG + dB2);
        fg[0]=t0.x; fg[1]=t0.y; fg[2]=t0.z; fg[3]=t0.w; fg[4]=t1.x; fg[5]=t1.y; fg[6]=t1.z; fg[7]=t1.w;
        t0 = *(const float4*)(lfB + dA); t1 = *(const float4*)(lfB + dB2);
        fb[0]=t0.x; fb[1]=t0.y; fb[2]=t0.z; fb[3]=t0.w; fb[4]=t1.x; fb[5]=t1.y; fb[6]=t1.z; fb[7]=t1.w;
    }
    const float* fp = gF + (size_t)blk * S_ * D_;
    const float* xp = gX + (size_t)blk * S_ * D_;
    __hip_bfloat16* op = xfO + (size_t)blk * S_ * D_;

    // 4-deep register pipeline: buffer u holds row (t + u); prefetch row t+u+4
    // immediately after consuming buffer u.  Clamped index -> no tail branch.
    float4 pf0[4], pf1[4], px0[4], px1[4];
    #pragma unroll
    for (int u = 0; u < 4; ++u) {
        const float* fq = fp + (size_t)u * D_;
        const float* xq = xp + (size_t)u * D_;
        pf0[u] = *(const float4*)(fq + dA);
        pf1[u] = *(const float4*)(fq + dB2);
        px0[u] = *(const float4*)(xq + dA);
        px1[u] = *(const float4*)(xq + dB2);
    }

    auto process = [&](int t, float4 f0, float4 f1, float4 x0, float4 x1) {
        float fv[8] = {f0.x, f0.y, f0.z, f0.w, f1.x, f1.y, f1.z, f1.w};
        float xv[8] = {x0.x, x0.y, x0.z, x0.w, x1.x, x1.y, x1.z, x1.w};
        float hr[8];
        float s = 0.f, q = 0.f;
        #pragma unroll
        for (int j = 0; j < 8; ++j) {
            hr[j] = fv[j] * (h[j] - xv[j]) + xv[j];  // f*h + (1-f)*x
            s += hr[j];
            q += hr[j] * hr[j];
        }
        const float S = wave_sum(s);
        const float Q = wave_sum(q);
        const float mean = S * (1.0f / 512.0f);
        const float var = Q * (1.0f / 512.0f) - mean * mean;
        const float rs = rsqrtf(var + 1e-5f);
        float s2 = 0.f, q2 = 0.f;
        #pragma unroll
        for (int j = 0; j < 8; ++j) {
            float hn = (hr[j] - mean) * rs * lg[j] + lb[j] + h[j];
            h[j] = hn;
            s2 += hn;
            q2 += hn * hn;
        }
        const float S2 = wave_sum(s2);
        const float Q2 = wave_sum(q2);
        const float m2 = S2 * (1.0f / 512.0f);
        const float rs2 = rsqrtf(Q2 * (1.0f / 512.0f) - m2 * m2 + 1e-5f);
        union { __hip_bfloat16 hh[4]; uint2 u; } p0, p1;
        #pragma unroll
        for (int j = 0; j < 4; ++j) p0.hh[j] = __float2bfloat16((h[j] - m2) * rs2 * fg[j] + fb[j]);
        #pragma unroll
        for (int j = 0; j < 4; ++j) p1.hh[j] = __float2bfloat16((h[4 + j] - m2) * rs2 * fg[4 + j] + fb[4 + j]);
        __hip_bfloat16* orow = op + (size_t)t * D_;
        *(uint2*)(orow + dA) = p0.u;
        *(uint2*)(orow + dB2) = p1.u;
    };

    for (int t = 0; t < S_; t += 4) {
        #pragma unroll
        for (int u = 0; u < 4; ++u) {
            process(t + u, pf0[u], pf1[u], px0[u], px1[u]);
            int tn = t + u + 4;
            if (tn > S_ - 1) tn = S_ - 1;   // clamped redundant prefetch at tail
            const float* fq = fp + (size_t)tn * D_;
            const float* xq = xp + (size_t)tn * D_;
            pf0[u] = *(const float4*)(fq + dA);
            pf1[u] = *(const float4*)(fq + dB2);
            px0[u] = *(const float4*)(xq + dA);
            px1[u] = *(const float4*)(xq + dB2);
        }
    }
}

// ---------------------------------------------------------------------------
// K4: logits = xf[8192,512] @ E^T  (NT GEMM), bf16 MFMA 16x16x32, 128x128 tile,
// BK=32, 4 waves each 64x64, global_load_lds width-16 staging (m97 structure).
// EB=true: B already bf16 in ws; EB=false: convert fp32 E in-tile.
// ---------------------------------------------------------------------------
template <bool EB>
__global__ __launch_bounds__(256) void k4_logits(
    const __hip_bfloat16* __restrict__ A,
    const __hip_bfloat16* __restrict__ Bb,
    const float* __restrict__ Bf,
    float* __restrict__ C)
{
    __shared__ __hip_bfloat16 sA[128 * 32];
    __shared__ __hip_bfloat16 sB[128 * 32];
    const int tid = threadIdx.x;
    const int wave = tid >> 6;
    const int lane = tid & 63;
    const int n0 = blockIdx.x * 128;
    const int m0 = blockIdx.y * 128;
    const int wm = (wave >> 1) * 64;
    const int wn = (wave & 1) * 64;
    const int c0 = wave * 128 + lane;
    const int c1 = c0 + 64;
    const int r0 = c0 >> 2, kc0 = (c0 & 3) * 8;
    const int r1 = c1 >> 2, kc1 = (c1 & 3) * 8;
    const int fr = lane & 15;
    const int kq = (lane >> 4) * 8;
    f32x4 acc[4][4] = {};
    for (int k0 = 0; k0 < D_; k0 += 32) {
        __syncthreads();
        __builtin_amdgcn_global_load_lds(
            (const __attribute__((address_space(1))) void*)(A + (size_t)(m0 + r0) * D_ + k0 + kc0),
            (__attribute__((address_space(3))) void*)(sA + wave * 1024), 16, 0, 0);
        __builtin_amdgcn_global_load_lds(
            (const __attribute__((address_space(1))) void*)(A + (size_t)(m0 + r1) * D_ + k0 + kc1),
            (__attribute__((address_space(3))) void*)(sA + wave * 1024 + 512), 16, 0, 0);
        if (EB) {
            __builtin_amdgcn_global_load_lds(
                (const __attribute__((address_space(1))) void*)(Bb + (size_t)(n0 + r0) * D_ + k0 + kc0),
                (__attribute__((address_space(3))) void*)(sB + wave * 1024), 16, 0, 0);
            __builtin_amdgcn_global_load_lds(
                (const __attribute__((address_space(1))) void*)(Bb + (size_t)(n0 + r1) * D_ + k0 + kc1),
                (__attribute__((address_space(3))) void*)(sB + wave * 1024 + 512), 16, 0, 0);
        } else {
            #pragma unroll
            for (int jj = 0; jj < 2; ++jj) {
                const int c = (jj == 0) ? c0 : c1;
                const int rr = c >> 2, kk = (c & 3) * 8;
                const float* gb = Bf + (size_t)(n0 + rr) * D_ + k0 + kk;
                float4 v0 = *(const float4*)gb;
                float4 v1 = *(const float4*)(gb + 4);
                union { __hip_bfloat16 hh[8]; uint4 u; } pk;
                pk.hh[0] = __float2bfloat16(v0.x); pk.hh[1] = __float2bfloat16(v0.y);
                pk.hh[2] = __float2bfloat16(v0.z); pk.hh[3] = __float2bfloat16(v0.w);
                pk.hh[4] = __float2bfloat16(v1.x); pk.hh[5] = __float2bfloat16(v1.y);
                pk.hh[6] = __float2bfloat16(v1.z); pk.hh[7] = __float2bfloat16(v1.w);
                *(uint4*)(sB + c * 8) = pk.u;
            }
        }
        __syncthreads();
        bf16x8 fa[4], fbr[4];
        #pragma unroll
        for (int i = 0; i < 4; ++i) {
            fa[i]  = *(const bf16x8*)(sA + (wm + i * 16 + fr) * 32 + kq);
            fbr[i] = *(const bf16x8*)(sB + (wn + i * 16 + fr) * 32 + kq);
        }
        #pragma unroll
        for (int i = 0; i < 4; ++i)
            #pragma unroll
            for (int j = 0; j < 4; ++j)
                acc[i][j] = __builtin_amdgcn_mfma_f32_16x16x32_bf16(fa[i], fbr[j], acc[i][j], 0, 0, 0);
    }
    const int cm = (lane >> 4) * 4;
    const int cn = lane & 15;
    #pragma unroll
    for (int i = 0; i < 4; ++i)
        #pragma unroll
        for (int j = 0; j < 4; ++j) {
            float* cp = C + (size_t)(m0 + wm + i * 16 + cm) * V_ + (n0 + wn + j * 16 + cn);
            #pragma unroll
            for (int r = 0; r < 4; ++r)
                cp[(size_t)r * V_] = acc[i][j][r];
        }
}

// ---------------------------------------------------------------------------
extern "C" void kernel_launch(void* const* d_in, const int* in_sizes, int n_in,
                              void* d_out, int out_size, void* d_ws, size_t ws_size,
                              hipStream_t stream)
{
    (void)in_sizes; (void)n_in; (void)out_size;
    const int* tok = (const int*)d_in[0];
    const float* E = (const float*)d_in[1];
    const float* Wih = (const float*)d_in[2];
    const float* bh = (const float*)d_in[3];
    const float* W1 = (const float*)d_in[4];
    const float* b1 = (const float*)d_in[5];
    const float* W2 = (const float*)d_in[6];
    const float* b2 = (const float*)d_in[7];
    const float* lng = (const float*)d_in[8];
    const float* lnb = (const float*)d_in[9];
    const float* h0 = (const float*)d_in[10];
    const float* lfg = (const float*)d_in[11];
    const float* lfb = (const float*)d_in[12];
    float* out = (float*)d_out;

    // ws layout (tier A): f[M,D] f32 | x[M,D] f32 | xf[M,D] bf16 | Eb[V,D] bf16
    const size_t needA = (size_t)M_ * D_ * 10 + (size_t)V_ * D_ * 2;  // 74.7 MB
    const bool tierA = ws_size >= needA;

    float *fB, *xB;
    __hip_bfloat16 *xf, *Eb;
    if (tierA) {
        fB = (float*)d_ws;
        xB = fB + (size_t)M_ * D_;
        xf = (__hip_bfloat16*)(xB + (size_t)M_ * D_);
        Eb = xf + (size_t)M_ * D_;
    } else {
        // stash f/x in the dead tail of d_out (overwritten only by k4 at the end)
        const size_t out_bytes = (size_t)M_ * V_ * 4;               // 1,048,576,000
        const size_t fx_bytes = (size_t)M_ * D_ * 8;                // 33,554,432
        fB = (float*)((char*)d_out + (out_bytes - fx_bytes));
        xB = fB + (size_t)M_ * D_;
        xf = (__hip_bfloat16*)d_ws;                                 // needs 8.4 MB
        Eb = nullptr;
    }

    k1_fx<<<dim3(64, 8, 2), 256, 0, stream>>>(tok, E, Wih, bh, W1, b1, W2, b2, fB, xB);
    if (tierA) {
        k2_scan<<<dim3(B_ + 16000), 64, 0, stream>>>(fB, xB, lng, lnb, h0, lfg, lfb, E, xf, Eb);
        k4_logits<true><<<dim3(250, 64), 256, 0, stream>>>(xf, Eb, nullptr, out);
    } else {
        k2_scan<<<dim3(B_), 64, 0, stream>>>(fB, xB, lng, lnb, h0, lfg, lfb, E, xf, nullptr);
        k4_logits<false><<<dim3(250, 64), 256, 0, stream>>>(xf, nullptr, E, out);
    }
}